// Round 2
// baseline (86.984 us; speedup 1.0000x reference)
//
#include <hip/hip_runtime.h>
#include <math.h>

// PCEN transform: EMA over time (s=0.025) + (x/(M+eps)^0.98 + 2)^0.5 - 2^0.5
// x: [B=32, T=8192, F=128] f32 -> out same shape f32.
//
// Strategy: chunk T into K=32 chunks of C=256. Each chunk re-runs a W=256
// warm-up EMA (a^256 ~ 1.6e-3 forgetting => output err ~5e-3 << 9.5e-2
// threshold). Chunk 0 exact from t=0; chunk 1's warm-up reaches t=0 (exact).
// Warm-up re-reads hit L2/L3 (input 134MB < 256MB L3), so HBM traffic stays
// ~= 1 read + 1 write.

#define BB 32
#define TT 8192
#define FF 128
#define KK 32            // chunks per chain
#define CC (TT / KK)     // 256 time steps per chunk
#define WW 256           // warm-up steps

__device__ __forceinline__ float pcen_out(float xv, float m) {
    float mp = m + 1e-6f;
    // (m+eps)^(-0.98) via v_exp_f32 / v_log_f32
    float p = __builtin_amdgcn_exp2f(-0.98f * __builtin_amdgcn_logf(mp));
    return sqrtf(fmaf(xv, p, 2.0f)) - 1.41421356237309505f;
}

__global__ __launch_bounds__(128) void pcen_kernel(const float* __restrict__ x,
                                                   float* __restrict__ out) {
    const int job = blockIdx.x;          // b * KK + k
    const int b   = job >> 5;            // job / KK
    const int k   = job & (KK - 1);      // job % KK
    const int f   = threadIdx.x;         // 0..127
    const int t0  = k * CC;

    const size_t base = ((size_t)b * TT + t0) * FF + f;
    const float* xp = x + base;
    float*       op = out + base;

    float m;
    if (k == 0) {
        // exact: M[0] = x[0]
        float xv = xp[0];
        m = xv;
        op[0] = pcen_out(xv, m);
    } else {
        // warm-up EMA over [t0-WW, t0): init with x[t0-WW] ~ M[t0-WW]
        const float* wp = xp - (size_t)WW * FF;
        m = wp[0];
        #pragma unroll 8
        for (int j = 1; j < WW; ++j) {
            m = fmaf(0.975f, m, 0.025f * wp[(size_t)j * FF]);
        }
        // j = 0 of the main chunk
        float xv = xp[0];
        m = fmaf(0.975f, m, 0.025f * xv);
        op[0] = pcen_out(xv, m);
    }

    #pragma unroll 4
    for (int j = 1; j < CC; ++j) {
        float xv = xp[(size_t)j * FF];
        m = fmaf(0.975f, m, 0.025f * xv);
        op[(size_t)j * FF] = pcen_out(xv, m);
    }
}

extern "C" void kernel_launch(void* const* d_in, const int* in_sizes, int n_in,
                              void* d_out, int out_size, void* d_ws, size_t ws_size,
                              hipStream_t stream) {
    const float* x = (const float*)d_in[0];
    float* out = (float*)d_out;
    (void)in_sizes; (void)n_in; (void)out_size; (void)d_ws; (void)ws_size;
    pcen_kernel<<<BB * KK, 128, 0, stream>>>(x, out);
}

// Round 3
// 83.935 us; speedup vs baseline: 1.0363x; 1.0363x over previous
//
#include <hip/hip_runtime.h>
#include <math.h>

// PCEN transform: EMA over time (s=0.025) + (x/(M+eps)^0.98 + 2)^0.5 - 2^0.5
// x: [B=32, T=8192, F=128] f32 -> out same shape f32.
//
// Strategy: chunk T into K=64 chunks of C=128. Each chunk re-runs a
// W=min(256,t0) warm-up EMA (a^256 ~ 1.6e-3 forgetting => output err ~4e-3
// << 9.5e-2 threshold; chunks 0..2 are exact since warm-up reaches t=0).
// Warm-up re-reads hit L3 (input 134MB < 256MB L3), so HBM traffic stays
// ~= 1 read + 1 write. Stores are nontemporal so writes don't evict x.
//
// R2 -> R3: KK 32->64 (8->16 waves/CU: latency-bound at 15% occupancy),
// unroll 8 for deeper load pipelining.

#define BB 32
#define TT 8192
#define FF 128
#define KK 64            // chunks per chain
#define CC (TT / KK)     // 128 time steps per chunk
#define WW 256           // max warm-up steps
#define AA 0.975f
#define SS 0.025f

__device__ __forceinline__ float pcen_out(float xv, float m) {
    float mp = m + 1e-6f;
    // (m+eps)^(-0.98) via v_exp_f32 / v_log_f32
    float p = __builtin_amdgcn_exp2f(-0.98f * __builtin_amdgcn_logf(mp));
    return sqrtf(fmaf(xv, p, 2.0f)) - 1.41421356237309505f;
}

__global__ __launch_bounds__(128) void pcen_kernel(const float* __restrict__ x,
                                                   float* __restrict__ out) {
    const int job = blockIdx.x;          // b * KK + k
    const int b   = job >> 6;            // job / KK
    const int k   = job & (KK - 1);      // job % KK
    const int f   = threadIdx.x;         // 0..127
    const int t0  = k * CC;

    const size_t base = ((size_t)b * TT + t0) * FF + f;
    const float* xp = x + base;
    float*       op = out + base;

    float m;
    if (k == 0) {
        // exact: M[0] = x[0]
        float xv = xp[0];
        m = xv;
        __builtin_nontemporal_store(pcen_out(xv, m), op);
    } else {
        // warm-up EMA over [t0-w, t0); exact when w reaches t=0 (k=1,2)
        const int w = (t0 < WW) ? t0 : WW;
        const float* wp = xp - (size_t)w * FF;
        m = wp[0];
        #pragma unroll 8
        for (int j = 1; j < w; ++j) {
            m = fmaf(AA, m, SS * wp[(size_t)j * FF]);
        }
        // j = 0 of the main chunk
        float xv = xp[0];
        m = fmaf(AA, m, SS * xv);
        __builtin_nontemporal_store(pcen_out(xv, m), op);
    }

    #pragma unroll 8
    for (int j = 1; j < CC; ++j) {
        float xv = xp[(size_t)j * FF];
        m = fmaf(AA, m, SS * xv);
        __builtin_nontemporal_store(pcen_out(xv, m), op + (size_t)j * FF);
    }
}

extern "C" void kernel_launch(void* const* d_in, const int* in_sizes, int n_in,
                              void* d_out, int out_size, void* d_ws, size_t ws_size,
                              hipStream_t stream) {
    const float* x = (const float*)d_in[0];
    float* out = (float*)d_out;
    (void)in_sizes; (void)n_in; (void)out_size; (void)d_ws; (void)ws_size;
    pcen_kernel<<<BB * KK, 128, 0, stream>>>(x, out);
}